// Round 15
// baseline (135.940 us; speedup 1.0000x reference)
//
#include <hip/hip_runtime.h>
#include <hip/hip_bf16.h>
#include <cstdint>
#include <cstddef>

#define BB 256
#define RR 512
#define AA 196
#define VV 10000
#define MATT (BB*AA)   // 50176 = 196 * 256
#define NT13 13        // 13*16 = 208 cols

typedef float f32x4 __attribute__((ext_vector_type(4)));
typedef __bf16 bf16x8 __attribute__((ext_vector_type(8)));
typedef __bf16 bf16x4 __attribute__((ext_vector_type(4)));

#define MFMA16(a,b,c) __builtin_amdgcn_mfma_f32_16x16x32_bf16(a,b,c,0,0,0)

__device__ __forceinline__ float fast_tanh(float x){
  float ax = fabsf(x);
  float e = __expf(-2.0f*ax);
  float t = __fdividef(1.0f - e, 1.0f + e);
  return x < 0.0f ? -t : t;
}

__device__ __forceinline__ void gload16(const void* gsrc, void* ldsdst){
  __builtin_amdgcn_global_load_lds(
      (const __attribute__((address_space(1))) unsigned int*)gsrc,
      (__attribute__((address_space(3))) unsigned int*)ldsdst,
      16, 0, 0);
}

#define ABAR   asm volatile("s_barrier" ::: "memory")
#define WVM(N) asm volatile("s_waitcnt vmcnt(" #N ")" ::: "memory")

#define CVT8(a, f0, f1) do { \
  a[0]=(__bf16)(f0).x; a[1]=(__bf16)(f0).y; a[2]=(__bf16)(f0).z; a[3]=(__bf16)(f0).w; \
  a[4]=(__bf16)(f1).x; a[5]=(__bf16)(f1).y; a[6]=(__bf16)(f1).z; a[7]=(__bf16)(f1).w; \
} while(0)

// ---------- single fused prep kernel (unchanged) ----------
__global__ void prep_all_k(
    const float* __restrict__ Wa2a, const float* __restrict__ Wh2a,
    const float* __restrict__ Wproj, const float* __restrict__ inputs,
    const float* __restrict__ Wi2h, const float* __restrict__ Wh2h,
    const float* __restrict__ Wr2a, const float* __restrict__ ba2a,
    const float* __restrict__ wd2d, const float* __restrict__ bi2h,
    const float* __restrict__ bh2h, const float* __restrict__ br2a,
    __bf16* __restrict__ Wa2a_p, __bf16* __restrict__ Wh2a_pad,
    __bf16* __restrict__ Wproj_bf, __bf16* __restrict__ inp_bf,
    __bf16* __restrict__ Wcat_bf,
    float* __restrict__ ba_pad, float* __restrict__ wd_pad, float* __restrict__ bcat)
{
  size_t q = (size_t)blockIdx.x*256 + threadIdx.x;
  float4 v = {0,0,0,0};
  __bf16* dst = nullptr;
  size_t dq = 0;
  if (q < 32768){
    int row = q >> 7, k4 = q & 127;
    if (row < AA) v = ((const float4*)(Wa2a + (size_t)row*512))[k4];
    dst = Wa2a_p; dq = q;
  } else if (q < 65536){
    size_t ql = q - 32768;
    int row = ql >> 7, k4 = ql & 127;
    if (row < AA) v = ((const float4*)(Wh2a + (size_t)row*512))[k4];
    dst = Wh2a_pad; dq = ql;
  } else if (q < 1351680){
    size_t ql = q - 65536;
    int row = ql >> 7, k4 = ql & 127;
    if (row < VV) v = ((const float4*)(Wproj + (size_t)row*512))[k4];
    dst = Wproj_bf; dq = ql;
  } else if (q < 1417216){
    size_t ql = q - 1351680;
    const float* src = (ql < 32768) ? (inputs + 1*131072) : (inputs + 3*131072 - 131072);
    v = ((const float4*)src)[ql];
    dst = inp_bf; dq = ql;
  } else if (q < 2203648){
    size_t ql = q - 1417216;
    int n = ql / 384, k4 = ql - (size_t)n*384;
    if (k4 < 128)      v = ((const float4*)(Wi2h + (size_t)n*512))[k4];
    else if (k4 < 256) v = ((const float4*)(Wh2h + (size_t)n*512))[k4-128];
    else               v = ((const float4*)(Wr2a + (size_t)n*512))[k4-256];
    dst = Wcat_bf; dq = (size_t)n*384 + k4;
  } else {
    size_t i = q - 2203648;
    if (i < 2048)       bcat[i] = bi2h[i] + bh2h[i] + br2a[i];
    else if (i < 2304){ int j = i - 2048; ba_pad[j] = (j < AA) ? ba2a[j] : 0.0f; }
    else              { int j = i - 2304; wd_pad[j] = (j < AA) ? wd2d[j] : 0.0f; }
    return;
  }
  bf16x4 o;
  o[0]=(__bf16)v.x; o[1]=(__bf16)v.y; o[2]=(__bf16)v.z; o[3]=(__bf16)v.w;
  ((bf16x4*)dst)[dq] = o;
}

// ---------- gemm4: BM=64, BN=64, K-chunk 64, 3-buf counted vmcnt; CB=1 -> bf16 C ----------
// Wave w owns cols [ncb+w*16,+16) x all 64 rows (4 row-frags). Halves B re-read vs BM=32.
template<int CB>
__global__ __launch_bounds__(256,4) void gemm4_k(
    const __bf16* __restrict__ A, const __bf16* __restrict__ Bw,
    const float* __restrict__ bias, void* __restrict__ Cv,
    int N, int K, int NC)
{
  __shared__ __bf16 AshAll[3*4096];   // 3 x [64][64]
  __shared__ __bf16 BshAll[3*4096];   // 3 x [64][64]
  const int t = threadIdx.x;
  const int l = t & 63;
  const int w = t >> 6;
  const int l15 = l & 15;
  const int g  = l >> 4;
  const int rho = l15 & 7;
  const int mrow = blockIdx.y*64;
  const int ncb  = blockIdx.x*64;

  // staging: 512 slots of 16B per tile; slot s -> row=s>>3, j=s&7; 2 gloads each
  const __bf16* aS[2]; const __bf16* bS[2]; int off[2];
  #pragma unroll
  for (int i = 0; i < 2; i++){
    int slot = i*256 + t;
    int row = slot >> 3, j = slot & 7;
    off[i] = (i*256 + w*64) * 8;      // wave-uniform elem offset
    aS[i] = A  + (size_t)(mrow + row)*K + ((j ^ (row&7)) << 3);
    bS[i] = Bw + (size_t)(ncb  + row)*K + ((j ^ (row&7)) << 3);
  }

#define G4_STAGE(B, CH) do { \
    gload16(aS[0] + (CH)*64, AshAll + (B)*4096 + off[0]); \
    gload16(aS[1] + (CH)*64, AshAll + (B)*4096 + off[1]); \
    gload16(bS[0] + (CH)*64, BshAll + (B)*4096 + off[0]); \
    gload16(bS[1] + (CH)*64, BshAll + (B)*4096 + off[1]); \
  } while(0)

  f32x4 acc[4] = {};

#define G4_COMPUTE(B) do { \
    const __bf16* As_ = AshAll + (B)*4096; \
    const __bf16* Bs_ = BshAll + (B)*4096; \
    _Pragma("unroll") \
    for (int s_ = 0; s_ < 2; s_++){ \
      int q_ = (((s_<<2)+g) ^ rho) << 3; \
      bf16x8 b_ = *(const bf16x8*)(Bs_ + (w*16+l15)*64 + q_); \
      _Pragma("unroll") \
      for (int rf_ = 0; rf_ < 4; rf_++){ \
        bf16x8 a_ = *(const bf16x8*)(As_ + (l15 + rf_*16)*64 + q_); \
        acc[rf_] = MFMA16(a_, b_, acc[rf_]); \
      } \
    } \
  } while(0)

  G4_STAGE(0,0); G4_STAGE(1,1); G4_STAGE(2,2);
  WVM(8); ABAR;
  int buf = 0;
  for (int c = 0; c < NC; c++){
    G4_COMPUTE(buf);
    if (c + 3 < NC){
      ABAR;
      G4_STAGE(buf, c+3);
      WVM(8); ABAR;
    } else if (c == NC-3){
      WVM(4); ABAR;
    } else if (c == NC-2){
      WVM(0); ABAR;
    }
    buf = (buf == 2) ? 0 : buf + 1;
  }

  int col = ncb + w*16 + l15;
  if (col < N){
    float bv = bias[col];
    #pragma unroll
    for (int rf = 0; rf < 4; rf++){
      #pragma unroll
      for (int r = 0; r < 4; r++){
        float v = acc[rf][r] + bv;
        size_t idx = (size_t)(mrow + rf*16 + g*4 + r)*N + col;
        if constexpr (CB == 1) ((__bf16*)Cv)[idx] = (__bf16)v;
        else                   ((float*)Cv)[idx] = v;
      }
    }
  }
#undef G4_STAGE
#undef G4_COMPUTE
}

// ---------- att_score5s (structural floor, unchanged from R14) ----------
__global__ __launch_bounds__(256,2) void att_score5s_k(
    const float* __restrict__ att, const __bf16* __restrict__ Wa2a_p,
    const float* __restrict__ ba_pad, const float* __restrict__ wd_pad,
    const float* __restrict__ att_h, float* __restrict__ score)
{
  __shared__ __bf16 Bsh[3*13312];   // 3 x [208][64], 78 KB
  const int t = threadIdx.x;
  const int l = t & 63;
  const int w = t >> 6;
  const int l15 = l & 15;
  const int g  = l >> 4;
  const int bid = blockIdx.x;
  const int tile = (bid & 7) * 98 + (bid >> 3);   // 784 = 8*98 bijective XCD swizzle
  const int rowbase = tile * 64;

  const __bf16* bsrc[7]; int bslot[7];
  #pragma unroll
  for (int i = 0; i < 7; i++){
    int id = i*4 + w;
    if (id >= 26) id -= 2;
    int slotbase = id*64;
    int slot = slotbase + l;
    int row = slot >> 3;
    int j   = slot & 7;
    bslot[i] = slotbase*8;
    bsrc[i]  = Wa2a_p + (size_t)row*RR + ((j ^ (row&7))<<3);
  }

  const float* pa = att + (size_t)(rowbase + w*16 + l15)*RR + g*8;

  f32x4 acc[NT13] = {};
  float4 p00,p01,p02,p03, p10,p11,p12,p13, p20,p21,p22,p23;

#define SC_STAGE(B, KC) do { \
    _Pragma("unroll") \
    for (int i_ = 0; i_ < 7; i_++) gload16(bsrc[i_] + (KC), Bsh + (B)*13312 + bslot[i_]); \
  } while(0)
#define SC_LOADA(S, KC) do { \
    p##S##0 = *(const float4*)(pa + (KC)); \
    p##S##1 = *(const float4*)(pa + (KC) + 4); \
    p##S##2 = *(const float4*)(pa + (KC) + 32); \
    p##S##3 = *(const float4*)(pa + (KC) + 36); \
  } while(0)
#define SC_COMPUTE(B, S) do { \
    { bf16x8 a_; CVT8(a_, p##S##0, p##S##1); \
      const int sw_ = (g ^ (l15 & 7)) << 3; \
      _Pragma("unroll") \
      for (int nt_ = 0; nt_ < NT13; nt_++){ \
        bf16x8 b_ = *(const bf16x8*)&Bsh[(B)*13312 + nt_*1024 + l15*64 + sw_]; \
        acc[nt_] = MFMA16(a_, b_, acc[nt_]); } } \
    { bf16x8 a_; CVT8(a_, p##S##2, p##S##3); \
      const int sw_ = ((4 + g) ^ (l15 & 7)) << 3; \
      _Pragma("unroll") \
      for (int nt_ = 0; nt_ < NT13; nt_++){ \
        bf16x8 b_ = *(const bf16x8*)&Bsh[(B)*13312 + nt_*1024 + l15*64 + sw_]; \
        acc[nt_] = MFMA16(a_, b_, acc[nt_]); } } \
  } while(0)

  SC_STAGE(0,0);   SC_LOADA(0,0);
  SC_STAGE(1,64);  SC_LOADA(1,64);
  SC_STAGE(2,128); SC_LOADA(2,128);
  WVM(22); ABAR;
  SC_COMPUTE(0,0); ABAR; SC_STAGE(0,192); SC_LOADA(0,192); WVM(22); ABAR;  // c=0
  SC_COMPUTE(1,1); ABAR; SC_STAGE(1,256); SC_LOADA(1,256); WVM(22); ABAR;  // c=1
  SC_COMPUTE(2,2); ABAR; SC_STAGE(2,320); SC_LOADA(2,320); WVM(22); ABAR;  // c=2
  SC_COMPUTE(0,0); ABAR; SC_STAGE(0,384); SC_LOADA(0,384); WVM(22); ABAR;  // c=3
  SC_COMPUTE(1,1); ABAR; SC_STAGE(1,448); SC_LOADA(1,448); WVM(22); ABAR;  // c=4
  SC_COMPUTE(2,2); WVM(11); ABAR;                                          // c=5
  SC_COMPUTE(0,0); WVM(0);  ABAR;                                          // c=6
  SC_COMPUTE(1,1);                                                         // c=7

  float wdv[NT13], bav[NT13];
  #pragma unroll
  for (int nt = 0; nt < NT13; nt++){
    int col = nt*16 + l15;
    wdv[nt] = wd_pad[col];
    bav[nt] = ba_pad[col];
  }
  #pragma unroll
  for (int r = 0; r < 4; r++){
    int row = rowbase + w*16 + g*4 + r;
    float ah0 = att_h[row];
    float ah1 = att_h[MATT + row];
    float s0 = 0.0f, s1 = 0.0f;
    #pragma unroll
    for (int nt = 0; nt < NT13; nt++){
      float v = acc[nt][r] + bav[nt];
      s0 += fast_tanh(v + ah0) * wdv[nt];
      s1 += fast_tanh(v + ah1) * wdv[nt];
    }
    #pragma unroll
    for (int o = 1; o < 16; o <<= 1){
      s0 += __shfl_xor(s0, o, 16);
      s1 += __shfl_xor(s1, o, 16);
    }
    if (l15 == 0){
      score[row] = s0;
      score[MATT + row] = s1;
    }
  }
#undef SC_STAGE
#undef SC_LOADA
#undef SC_COMPUTE
}

// ---------- fused softmax + att_res + Xcat fills (unchanged) ----------
__global__ __launch_bounds__(512) void attres_sm_k(
    const float* __restrict__ att, const float* __restrict__ score,
    const float* __restrict__ x, const float* __restrict__ inputs,
    __bf16* __restrict__ Xcat0, __bf16* __restrict__ Xcat1)
{
  int b = blockIdx.x, t = threadIdx.x;
  __shared__ float wv[2][256];
  __shared__ float4 redv[4][128];
  const int w = t >> 6, l = t & 63;

  if (w < 2){
    const float* s = score + (size_t)w*MATT + (size_t)b*AA;
    float v[4], e[4];
    #pragma unroll
    for (int j = 0; j < 4; j++){
      int i = l + j*64;
      v[j] = (i < AA) ? s[i] : -3.4e38f;
    }
    float mx = fmaxf(fmaxf(v[0],v[1]), fmaxf(v[2],v[3]));
    #pragma unroll
    for (int o = 1; o < 64; o <<= 1) mx = fmaxf(mx, __shfl_xor(mx, o, 64));
    float sum = 0.0f;
    #pragma unroll
    for (int j = 0; j < 4; j++){
      int i = l + j*64;
      e[j] = (i < AA) ? __expf(v[j] - mx) : 0.0f;
      sum += e[j];
    }
    #pragma unroll
    for (int o = 1; o < 64; o <<= 1) sum += __shfl_xor(sum, o, 64);
    float inv = 1.0f / sum;
    #pragma unroll
    for (int j = 0; j < 4; j++) wv[w][l + j*64] = e[j]*inv;
  }
  Xcat0[(size_t)b*1536 + t]       = (__bf16)x[(size_t)b*512 + t];
  Xcat0[(size_t)b*1536 + 512 + t] = (__bf16)inputs[(size_t)1*131072 + b*512 + t];
  Xcat1[(size_t)b*1536 + 512 + t] = (__bf16)inputs[(size_t)3*131072 + b*512 + t];
  __syncthreads();

  int cg = t & 127, ig = t >> 7;
  const float4* ap = (const float4*)(att + (size_t)b*AA*RR) + cg;
  float4 s0 = {0,0,0,0}, s1 = {0,0,0,0};
  #pragma unroll 4
  for (int i = ig; i < AA; i += 4){
    float4 v = ap[(size_t)i*128];
    float a0 = wv[0][i], a1 = wv[1][i];
    s0.x += v.x*a0; s0.y += v.y*a0; s0.z += v.z*a0; s0.w += v.w*a0;
    s1.x += v.x*a1; s1.y += v.y*a1; s1.z += v.z*a1; s1.w += v.w*a1;
  }
  redv[ig][cg] = s0; __syncthreads();
  if (t < 128){
    float4 a = redv[0][t], b4 = redv[1][t], c4 = redv[2][t], d4 = redv[3][t];
    bf16x4 o;
    o[0]=(__bf16)(a.x+b4.x+c4.x+d4.x); o[1]=(__bf16)(a.y+b4.y+c4.y+d4.y);
    o[2]=(__bf16)(a.z+b4.z+c4.z+d4.z); o[3]=(__bf16)(a.w+b4.w+c4.w+d4.w);
    *(bf16x4*)(Xcat0 + (size_t)b*1536 + 1024 + t*4) = o;
  }
  __syncthreads();
  redv[ig][cg] = s1; __syncthreads();
  if (t < 128){
    float4 a = redv[0][t], b4 = redv[1][t], c4 = redv[2][t], d4 = redv[3][t];
    bf16x4 o;
    o[0]=(__bf16)(a.x+b4.x+c4.x+d4.x); o[1]=(__bf16)(a.y+b4.y+c4.y+d4.y);
    o[2]=(__bf16)(a.z+b4.z+c4.z+d4.z); o[3]=(__bf16)(a.w+b4.w+c4.w+d4.w);
    *(bf16x4*)(Xcat1 + (size_t)b*1536 + 1024 + t*4) = o;
  }
}

// ---------- LSTM gates ----------
__global__ void gate_k(const float* __restrict__ sums, const float* __restrict__ prev_c,
                       float* __restrict__ out_c, float* __restrict__ out_h,
                       __bf16* __restrict__ hdst, int hstride){
  int idx = blockIdx.x*256 + threadIdx.x;
  int b = idx >> 9, r = idx & 511;
  const float* s = sums + (size_t)b*2048;
  float ig = 1.0f/(1.0f + __expf(-s[r]));
  float fg = 1.0f/(1.0f + __expf(-s[512+r]));
  float og = 1.0f/(1.0f + __expf(-s[1024+r]));
  float g  = fast_tanh(s[1536+r]);
  float c = fg*prev_c[idx] + ig*g;
  float h = og*fast_tanh(c);
  out_c[idx] = c;
  out_h[idx] = h;
  hdst[(size_t)b*hstride + r] = (__bf16)h;
}

// ---------- log_softmax over bf16 logits ----------
__global__ void logsoftmaxb_k(const __bf16* __restrict__ logits, float* __restrict__ out){
  int b = blockIdx.x, t = threadIdx.x;
  __shared__ float red[4], red2[4];
  const bf16x8* p = (const bf16x8*)(logits + (size_t)b*VV);   // 1250 vecs
  float mx = -3.4e38f;
  for (int i = t; i < 1250; i += 256){
    bf16x8 v = p[i];
    #pragma unroll
    for (int e = 0; e < 8; e++) mx = fmaxf(mx, (float)v[e]);
  }
  #pragma unroll
  for (int o = 1; o < 64; o <<= 1) mx = fmaxf(mx, __shfl_xor(mx, o, 64));
  if ((t & 63) == 0) red[t >> 6] = mx;
  __syncthreads();
  mx = fmaxf(fmaxf(red[0], red[1]), fmaxf(red[2], red[3]));
  float sum = 0.0f;
  for (int i = t; i < 1250; i += 256){
    bf16x8 v = p[i];
    #pragma unroll
    for (int e = 0; e < 8; e++) sum += __expf((float)v[e] - mx);
  }
  #pragma unroll
  for (int o = 1; o < 64; o <<= 1) sum += __shfl_xor(sum, o, 64);
  if ((t & 63) == 0) red2[t >> 6] = sum;
  __syncthreads();
  sum = red2[0] + red2[1] + red2[2] + red2[3];
  float lse = mx + logf(sum);
  float4* q = (float4*)(out + (size_t)b*VV);
  for (int i = t; i < 1250; i += 256){
    bf16x8 v = p[i];
    float4 o0, o1;
    o0.x=(float)v[0]-lse; o0.y=(float)v[1]-lse; o0.z=(float)v[2]-lse; o0.w=(float)v[3]-lse;
    o1.x=(float)v[4]-lse; o1.y=(float)v[5]-lse; o1.z=(float)v[6]-lse; o1.w=(float)v[7]-lse;
    q[i*2]   = o0;
    q[i*2+1] = o1;
  }
}

extern "C" void kernel_launch(void* const* d_in, const int* in_sizes, int n_in,
                              void* d_out_, int out_size, void* d_ws, size_t ws_size,
                              hipStream_t stream){
  const float* x     = (const float*)d_in[0];
  const float* att   = (const float*)d_in[1];
  const float* inputs= (const float*)d_in[2];
  const float* Wa2a  = (const float*)d_in[3];
  const float* ba2a  = (const float*)d_in[4];
  const float* Wh2a  = (const float*)d_in[5];
  const float* bh2a  = (const float*)d_in[6];
  const float* wd2d  = (const float*)d_in[7];
  // d_in[8] = bd2d : uniform pre-softmax scalar -> softmax-invariant, unused
  const float* Wi2h  = (const float*)d_in[9];
  const float* bi2h  = (const float*)d_in[10];
  const float* Wh2h  = (const float*)d_in[11];
  const float* bh2h  = (const float*)d_in[12];
  const float* Wr2a  = (const float*)d_in[13];
  const float* br2a  = (const float*)d_in[14];
  const float* Wproj = (const float*)d_in[15];
  const float* bproj = (const float*)d_in[16];
  float* d_out = (float*)d_out_;

  char* wsp = (char*)d_ws;
  auto alloc = [&](size_t bytes)->char*{
    char* p = wsp;
    wsp += (bytes + 255) & ~(size_t)255;
    return p;
  };
  __bf16* Wa2a_p   = (__bf16*)alloc((size_t)256*RR*2);
  __bf16* Wh2a_pad = (__bf16*)alloc((size_t)256*RR*2);
  __bf16* Wcat_bf  = (__bf16*)alloc((size_t)2048*1536*2);
  __bf16* Wproj_bf = (__bf16*)alloc((size_t)10048*RR*2);
  __bf16* inp_bf   = (__bf16*)alloc((size_t)512*RR*2);
  float* ba_pad = (float*)alloc(256*4);
  float* wd_pad = (float*)alloc(256*4);
  float* bcat   = (float*)alloc(2048*4);
  float* att_h  = (float*)alloc((size_t)2*MATT*4);
  float* score  = (float*)alloc((size_t)2*MATT*4);
  __bf16* Xcat0 = (__bf16*)alloc((size_t)BB*1536*2);
  __bf16* Xcat1 = (__bf16*)alloc((size_t)BB*1536*2);
  float* sums   = (float*)alloc((size_t)BB*2048*4);
  __bf16* h1_bf = (__bf16*)alloc((size_t)BB*RR*2);
  __bf16* logits= (__bf16*)alloc((size_t)BB*VV*2);

  // one fused prep launch
  prep_all_k<<<8618, 256, 0, stream>>>(
      Wa2a, Wh2a, Wproj, inputs, Wi2h, Wh2h, Wr2a, ba2a, wd2d, bi2h, bh2h, br2a,
      Wa2a_p, Wh2a_pad, Wproj_bf, inp_bf, Wcat_bf, ba_pad, wd_pad, bcat);

  // att_h for both layers (fixed inputs): [512 rows][196]
  gemm4_k<0><<<dim3(4,8), 256, 0, stream>>>(inp_bf, Wh2a_pad, bh2a, att_h, AA, 512, 8);

  // attention
  att_score5s_k<<<784, 256, 0, stream>>>(att, Wa2a_p, ba_pad, wd_pad, att_h, score);
  attres_sm_k<<<256, 512, 0, stream>>>(att, score, x, inputs, Xcat0, Xcat1);

  // layer 0
  gemm4_k<0><<<dim3(32,4), 256, 0, stream>>>(Xcat0, Wcat_bf, bcat, sums, 2048, 1536, 24);
  gate_k<<<512, 256, 0, stream>>>(sums, inputs, d_out, d_out + 131072, Xcat1, 1536);
  // layer 1
  gemm4_k<0><<<dim3(32,4), 256, 0, stream>>>(Xcat1, Wcat_bf, bcat, sums, 2048, 1536, 24);
  gate_k<<<512, 256, 0, stream>>>(sums, inputs + 2*131072, d_out + 2*131072, d_out + 3*131072, h1_bf, 512);

  // projection (bf16 logits) + log_softmax
  gemm4_k<1><<<dim3(157,4), 256, 0, stream>>>(h1_bf, Wproj_bf, bproj, logits, VV, 512, 8);
  logsoftmaxb_k<<<256, 256, 0, stream>>>(logits, d_out + 4*131072);
}

// Round 16
// 133.922 us; speedup vs baseline: 1.0151x; 1.0151x over previous
//
#include <hip/hip_runtime.h>
#include <hip/hip_bf16.h>
#include <cstdint>
#include <cstddef>

#define BB 256
#define RR 512
#define AA 196
#define VV 10000
#define MATT (BB*AA)   // 50176 = 196 * 256
#define NT13 13        // 13*16 = 208 cols

typedef float f32x4 __attribute__((ext_vector_type(4)));
typedef __bf16 bf16x8 __attribute__((ext_vector_type(8)));
typedef __bf16 bf16x4 __attribute__((ext_vector_type(4)));

#define MFMA16(a,b,c) __builtin_amdgcn_mfma_f32_16x16x32_bf16(a,b,c,0,0,0)

__device__ __forceinline__ float fast_tanh(float x){
  float ax = fabsf(x);
  float e = __expf(-2.0f*ax);
  float t = __fdividef(1.0f - e, 1.0f + e);
  return x < 0.0f ? -t : t;
}

__device__ __forceinline__ void gload16(const void* gsrc, void* ldsdst){
  __builtin_amdgcn_global_load_lds(
      (const __attribute__((address_space(1))) unsigned int*)gsrc,
      (__attribute__((address_space(3))) unsigned int*)ldsdst,
      16, 0, 0);
}

#define ABAR   asm volatile("s_barrier" ::: "memory")
#define WVM(N) asm volatile("s_waitcnt vmcnt(" #N ")" ::: "memory")

#define CVT8(a, f0, f1) do { \
  a[0]=(__bf16)(f0).x; a[1]=(__bf16)(f0).y; a[2]=(__bf16)(f0).z; a[3]=(__bf16)(f0).w; \
  a[4]=(__bf16)(f1).x; a[5]=(__bf16)(f1).y; a[6]=(__bf16)(f1).z; a[7]=(__bf16)(f1).w; \
} while(0)

// ---------- single fused prep kernel ----------
__global__ void prep_all_k(
    const float* __restrict__ Wa2a, const float* __restrict__ Wh2a,
    const float* __restrict__ Wproj, const float* __restrict__ inputs,
    const float* __restrict__ Wi2h, const float* __restrict__ Wh2h,
    const float* __restrict__ Wr2a, const float* __restrict__ ba2a,
    const float* __restrict__ wd2d, const float* __restrict__ bi2h,
    const float* __restrict__ bh2h, const float* __restrict__ br2a,
    __bf16* __restrict__ Wa2a_p, __bf16* __restrict__ Wh2a_pad,
    __bf16* __restrict__ Wproj_bf, __bf16* __restrict__ inp_bf,
    __bf16* __restrict__ Wcat_bf,
    float* __restrict__ ba_pad, float* __restrict__ wd_pad, float* __restrict__ bcat)
{
  size_t q = (size_t)blockIdx.x*256 + threadIdx.x;
  float4 v = {0,0,0,0};
  __bf16* dst = nullptr;
  size_t dq = 0;
  if (q < 32768){
    int row = q >> 7, k4 = q & 127;
    if (row < AA) v = ((const float4*)(Wa2a + (size_t)row*512))[k4];
    dst = Wa2a_p; dq = q;
  } else if (q < 65536){
    size_t ql = q - 32768;
    int row = ql >> 7, k4 = ql & 127;
    if (row < AA) v = ((const float4*)(Wh2a + (size_t)row*512))[k4];
    dst = Wh2a_pad; dq = ql;
  } else if (q < 1351680){
    size_t ql = q - 65536;
    int row = ql >> 7, k4 = ql & 127;
    if (row < VV) v = ((const float4*)(Wproj + (size_t)row*512))[k4];
    dst = Wproj_bf; dq = ql;
  } else if (q < 1417216){
    size_t ql = q - 1351680;
    const float* src = (ql < 32768) ? (inputs + 1*131072) : (inputs + 3*131072 - 131072);
    v = ((const float4*)src)[ql];
    dst = inp_bf; dq = ql;
  } else if (q < 2203648){
    size_t ql = q - 1417216;
    int n = ql / 384, k4 = ql - (size_t)n*384;
    if (k4 < 128)      v = ((const float4*)(Wi2h + (size_t)n*512))[k4];
    else if (k4 < 256) v = ((const float4*)(Wh2h + (size_t)n*512))[k4-128];
    else               v = ((const float4*)(Wr2a + (size_t)n*512))[k4-256];
    dst = Wcat_bf; dq = (size_t)n*384 + k4;
  } else {
    size_t i = q - 2203648;
    if (i < 2048)       bcat[i] = bi2h[i] + bh2h[i] + br2a[i];
    else if (i < 2304){ int j = i - 2048; ba_pad[j] = (j < AA) ? ba2a[j] : 0.0f; }
    else              { int j = i - 2304; wd_pad[j] = (j < AA) ? wd2d[j] : 0.0f; }
    return;
  }
  bf16x4 o;
  o[0]=(__bf16)v.x; o[1]=(__bf16)v.y; o[2]=(__bf16)v.z; o[3]=(__bf16)v.w;
  ((bf16x4*)dst)[dq] = o;
}

// ---------- pipelined bf16 GEMM; CB=1 writes bf16 C ----------
template<int CB>
__global__ __launch_bounds__(256,4) void gemm3_k(
    const __bf16* __restrict__ A, const __bf16* __restrict__ Bw,
    const float* __restrict__ bias, void* __restrict__ Cv,
    int N, int K, int NC)
{
  __shared__ __bf16 AshAll[3*2048];
  __shared__ __bf16 BshAll[3*4096];
  const int t = threadIdx.x;
  const int l = t & 63;
  const int w = t >> 6;
  const int l15 = l & 15;
  const int g  = l >> 4;
  const int rho = l15 & 7;
  const int mrow = blockIdx.y*32;
  const int ncb  = blockIdx.x*64;

  const int arow = t >> 3, aj = t & 7;
  const __bf16* as_ = A + (size_t)(mrow + arow)*K + ((aj ^ (arow&7)) << 3);
  const int aoff = w*512;
  const __bf16* bs0_ = Bw + (size_t)(ncb + arow)*K      + ((aj ^ (arow&7)) << 3);
  const __bf16* bs1_ = Bw + (size_t)(ncb + 32 + arow)*K + ((aj ^ (arow&7)) << 3);
  const int boff0 = w*512;
  const int boff1 = 2048 + w*512;

#define G3_STAGE(B, CH) do { \
    gload16(as_  + (CH)*64, AshAll + (B)*2048 + aoff); \
    gload16(bs0_ + (CH)*64, BshAll + (B)*4096 + boff0); \
    gload16(bs1_ + (CH)*64, BshAll + (B)*4096 + boff1); \
  } while(0)

  f32x4 acc0 = {}, acc1 = {};

#define G3_COMPUTE(B) do { \
    const __bf16* As_ = AshAll + (B)*2048; \
    const __bf16* Bs_ = BshAll + (B)*4096; \
    _Pragma("unroll") \
    for (int s_ = 0; s_ < 2; s_++){ \
      int q_ = (((s_<<2)+g) ^ rho) << 3; \
      bf16x8 a0_ = *(const bf16x8*)(As_ + l15*64 + q_); \
      bf16x8 a1_ = *(const bf16x8*)(As_ + (l15+16)*64 + q_); \
      bf16x8 b_  = *(const bf16x8*)(Bs_ + (w*16+l15)*64 + q_); \
      acc0 = MFMA16(a0_, b_, acc0); \
      acc1 = MFMA16(a1_, b_, acc1); \
    } \
  } while(0)

  G3_STAGE(0,0); G3_STAGE(1,1); G3_STAGE(2,2);
  WVM(6); ABAR;
  int buf = 0;
  for (int c = 0; c < NC; c++){
    G3_COMPUTE(buf);
    if (c + 3 < NC){
      ABAR;
      G3_STAGE(buf, c+3);
      WVM(6); ABAR;
    } else if (c == NC-3){
      WVM(3); ABAR;
    } else if (c == NC-2){
      WVM(0); ABAR;
    }
    buf = (buf == 2) ? 0 : buf + 1;
  }

  int col = ncb + w*16 + l15;
  if (col < N){
    float bv = bias[col];
    #pragma unroll
    for (int r = 0; r < 4; r++){
      float v0 = acc0[r] + bv;
      float v1 = acc1[r] + bv;
      if constexpr (CB == 1){
        __bf16* C = (__bf16*)Cv;
        C[(size_t)(mrow + g*4 + r)*N + col]      = (__bf16)v0;
        C[(size_t)(mrow + 16 + g*4 + r)*N + col] = (__bf16)v1;
      } else {
        float* C = (float*)Cv;
        C[(size_t)(mrow + g*4 + r)*N + col]      = v0;
        C[(size_t)(mrow + 16 + g*4 + r)*N + col] = v1;
      }
    }
  }
#undef G3_STAGE
#undef G3_COMPUTE
}

// ---------- att_score5s (structural floor; best measured 60-63 us) ----------
__global__ __launch_bounds__(256,2) void att_score5s_k(
    const float* __restrict__ att, const __bf16* __restrict__ Wa2a_p,
    const float* __restrict__ ba_pad, const float* __restrict__ wd_pad,
    const float* __restrict__ att_h, float* __restrict__ score)
{
  __shared__ __bf16 Bsh[3*13312];   // 3 x [208][64], 78 KB
  const int t = threadIdx.x;
  const int l = t & 63;
  const int w = t >> 6;
  const int l15 = l & 15;
  const int g  = l >> 4;
  const int bid = blockIdx.x;
  const int tile = (bid & 7) * 98 + (bid >> 3);   // 784 = 8*98 bijective XCD swizzle
  const int rowbase = tile * 64;

  const __bf16* bsrc[7]; int bslot[7];
  #pragma unroll
  for (int i = 0; i < 7; i++){
    int id = i*4 + w;
    if (id >= 26) id -= 2;
    int slotbase = id*64;
    int slot = slotbase + l;
    int row = slot >> 3;
    int j   = slot & 7;
    bslot[i] = slotbase*8;
    bsrc[i]  = Wa2a_p + (size_t)row*RR + ((j ^ (row&7))<<3);
  }

  const float* pa = att + (size_t)(rowbase + w*16 + l15)*RR + g*8;

  f32x4 acc[NT13] = {};
  float4 p00,p01,p02,p03, p10,p11,p12,p13, p20,p21,p22,p23;

#define SC_STAGE(B, KC) do { \
    _Pragma("unroll") \
    for (int i_ = 0; i_ < 7; i_++) gload16(bsrc[i_] + (KC), Bsh + (B)*13312 + bslot[i_]); \
  } while(0)
#define SC_LOADA(S, KC) do { \
    p##S##0 = *(const float4*)(pa + (KC)); \
    p##S##1 = *(const float4*)(pa + (KC) + 4); \
    p##S##2 = *(const float4*)(pa + (KC) + 32); \
    p##S##3 = *(const float4*)(pa + (KC) + 36); \
  } while(0)
#define SC_COMPUTE(B, S) do { \
    { bf16x8 a_; CVT8(a_, p##S##0, p##S##1); \
      const int sw_ = (g ^ (l15 & 7)) << 3; \
      _Pragma("unroll") \
      for (int nt_ = 0; nt_ < NT13; nt_++){ \
        bf16x8 b_ = *(const bf16x8*)&Bsh[(B)*13312 + nt_*1024 + l15*64 + sw_]; \
        acc[nt_] = MFMA16(a_, b_, acc[nt_]); } } \
    { bf16x8 a_; CVT8(a_, p##S##2, p##S##3); \
      const int sw_ = ((4 + g) ^ (l15 & 7)) << 3; \
      _Pragma("unroll") \
      for (int nt_ = 0; nt_ < NT13; nt_++){ \
        bf16x8 b_ = *(const bf16x8*)&Bsh[(B)*13312 + nt_*1024 + l15*64 + sw_]; \
        acc[nt_] = MFMA16(a_, b_, acc[nt_]); } } \
  } while(0)

  SC_STAGE(0,0);   SC_LOADA(0,0);
  SC_STAGE(1,64);  SC_LOADA(1,64);
  SC_STAGE(2,128); SC_LOADA(2,128);
  WVM(22); ABAR;
  SC_COMPUTE(0,0); ABAR; SC_STAGE(0,192); SC_LOADA(0,192); WVM(22); ABAR;  // c=0
  SC_COMPUTE(1,1); ABAR; SC_STAGE(1,256); SC_LOADA(1,256); WVM(22); ABAR;  // c=1
  SC_COMPUTE(2,2); ABAR; SC_STAGE(2,320); SC_LOADA(2,320); WVM(22); ABAR;  // c=2
  SC_COMPUTE(0,0); ABAR; SC_STAGE(0,384); SC_LOADA(0,384); WVM(22); ABAR;  // c=3
  SC_COMPUTE(1,1); ABAR; SC_STAGE(1,448); SC_LOADA(1,448); WVM(22); ABAR;  // c=4
  SC_COMPUTE(2,2); WVM(11); ABAR;                                          // c=5
  SC_COMPUTE(0,0); WVM(0);  ABAR;                                          // c=6
  SC_COMPUTE(1,1);                                                         // c=7

  float wdv[NT13], bav[NT13];
  #pragma unroll
  for (int nt = 0; nt < NT13; nt++){
    int col = nt*16 + l15;
    wdv[nt] = wd_pad[col];
    bav[nt] = ba_pad[col];
  }
  #pragma unroll
  for (int r = 0; r < 4; r++){
    int row = rowbase + w*16 + g*4 + r;
    float ah0 = att_h[row];
    float ah1 = att_h[MATT + row];
    float s0 = 0.0f, s1 = 0.0f;
    #pragma unroll
    for (int nt = 0; nt < NT13; nt++){
      float v = acc[nt][r] + bav[nt];
      s0 += fast_tanh(v + ah0) * wdv[nt];
      s1 += fast_tanh(v + ah1) * wdv[nt];
    }
    #pragma unroll
    for (int o = 1; o < 16; o <<= 1){
      s0 += __shfl_xor(s0, o, 16);
      s1 += __shfl_xor(s1, o, 16);
    }
    if (l15 == 0){
      score[row] = s0;
      score[MATT + row] = s1;
    }
  }
#undef SC_STAGE
#undef SC_LOADA
#undef SC_COMPUTE
}

// ---------- fused softmax + att_res + Xcat fills ----------
__global__ __launch_bounds__(512) void attres_sm_k(
    const float* __restrict__ att, const float* __restrict__ score,
    const float* __restrict__ x, const float* __restrict__ inputs,
    __bf16* __restrict__ Xcat0, __bf16* __restrict__ Xcat1)
{
  int b = blockIdx.x, t = threadIdx.x;
  __shared__ float wv[2][256];
  __shared__ float4 redv[4][128];
  const int w = t >> 6, l = t & 63;

  if (w < 2){
    const float* s = score + (size_t)w*MATT + (size_t)b*AA;
    float v[4], e[4];
    #pragma unroll
    for (int j = 0; j < 4; j++){
      int i = l + j*64;
      v[j] = (i < AA) ? s[i] : -3.4e38f;
    }
    float mx = fmaxf(fmaxf(v[0],v[1]), fmaxf(v[2],v[3]));
    #pragma unroll
    for (int o = 1; o < 64; o <<= 1) mx = fmaxf(mx, __shfl_xor(mx, o, 64));
    float sum = 0.0f;
    #pragma unroll
    for (int j = 0; j < 4; j++){
      int i = l + j*64;
      e[j] = (i < AA) ? __expf(v[j] - mx) : 0.0f;
      sum += e[j];
    }
    #pragma unroll
    for (int o = 1; o < 64; o <<= 1) sum += __shfl_xor(sum, o, 64);
    float inv = 1.0f / sum;
    #pragma unroll
    for (int j = 0; j < 4; j++) wv[w][l + j*64] = e[j]*inv;
  }
  Xcat0[(size_t)b*1536 + t]       = (__bf16)x[(size_t)b*512 + t];
  Xcat0[(size_t)b*1536 + 512 + t] = (__bf16)inputs[(size_t)1*131072 + b*512 + t];
  Xcat1[(size_t)b*1536 + 512 + t] = (__bf16)inputs[(size_t)3*131072 + b*512 + t];
  __syncthreads();

  int cg = t & 127, ig = t >> 7;
  const float4* ap = (const float4*)(att + (size_t)b*AA*RR) + cg;
  float4 s0 = {0,0,0,0}, s1 = {0,0,0,0};
  #pragma unroll 4
  for (int i = ig; i < AA; i += 4){
    float4 v = ap[(size_t)i*128];
    float a0 = wv[0][i], a1 = wv[1][i];
    s0.x += v.x*a0; s0.y += v.y*a0; s0.z += v.z*a0; s0.w += v.w*a0;
    s1.x += v.x*a1; s1.y += v.y*a1; s1.z += v.z*a1; s1.w += v.w*a1;
  }
  redv[ig][cg] = s0; __syncthreads();
  if (t < 128){
    float4 a = redv[0][t], b4 = redv[1][t], c4 = redv[2][t], d4 = redv[3][t];
    bf16x4 o;
    o[0]=(__bf16)(a.x+b4.x+c4.x+d4.x); o[1]=(__bf16)(a.y+b4.y+c4.y+d4.y);
    o[2]=(__bf16)(a.z+b4.z+c4.z+d4.z); o[3]=(__bf16)(a.w+b4.w+c4.w+d4.w);
    *(bf16x4*)(Xcat0 + (size_t)b*1536 + 1024 + t*4) = o;
  }
  __syncthreads();
  redv[ig][cg] = s1; __syncthreads();
  if (t < 128){
    float4 a = redv[0][t], b4 = redv[1][t], c4 = redv[2][t], d4 = redv[3][t];
    bf16x4 o;
    o[0]=(__bf16)(a.x+b4.x+c4.x+d4.x); o[1]=(__bf16)(a.y+b4.y+c4.y+d4.y);
    o[2]=(__bf16)(a.z+b4.z+c4.z+d4.z); o[3]=(__bf16)(a.w+b4.w+c4.w+d4.w);
    *(bf16x4*)(Xcat1 + (size_t)b*1536 + 1024 + t*4) = o;
  }
}

// ---------- LSTM gates ----------
__global__ void gate_k(const float* __restrict__ sums, const float* __restrict__ prev_c,
                       float* __restrict__ out_c, float* __restrict__ out_h,
                       __bf16* __restrict__ hdst, int hstride){
  int idx = blockIdx.x*256 + threadIdx.x;
  int b = idx >> 9, r = idx & 511;
  const float* s = sums + (size_t)b*2048;
  float ig = 1.0f/(1.0f + __expf(-s[r]));
  float fg = 1.0f/(1.0f + __expf(-s[512+r]));
  float og = 1.0f/(1.0f + __expf(-s[1024+r]));
  float g  = fast_tanh(s[1536+r]);
  float c = fg*prev_c[idx] + ig*g;
  float h = og*fast_tanh(c);
  out_c[idx] = c;
  out_h[idx] = h;
  hdst[(size_t)b*hstride + r] = (__bf16)h;
}

// ---------- log_softmax over bf16 logits ----------
__global__ void logsoftmaxb_k(const __bf16* __restrict__ logits, float* __restrict__ out){
  int b = blockIdx.x, t = threadIdx.x;
  __shared__ float red[4], red2[4];
  const bf16x8* p = (const bf16x8*)(logits + (size_t)b*VV);   // 1250 vecs
  float mx = -3.4e38f;
  for (int i = t; i < 1250; i += 256){
    bf16x8 v = p[i];
    #pragma unroll
    for (int e = 0; e < 8; e++) mx = fmaxf(mx, (float)v[e]);
  }
  #pragma unroll
  for (int o = 1; o < 64; o <<= 1) mx = fmaxf(mx, __shfl_xor(mx, o, 64));
  if ((t & 63) == 0) red[t >> 6] = mx;
  __syncthreads();
  mx = fmaxf(fmaxf(red[0], red[1]), fmaxf(red[2], red[3]));
  float sum = 0.0f;
  for (int i = t; i < 1250; i += 256){
    bf16x8 v = p[i];
    #pragma unroll
    for (int e = 0; e < 8; e++) sum += __expf((float)v[e] - mx);
  }
  #pragma unroll
  for (int o = 1; o < 64; o <<= 1) sum += __shfl_xor(sum, o, 64);
  if ((t & 63) == 0) red2[t >> 6] = sum;
  __syncthreads();
  sum = red2[0] + red2[1] + red2[2] + red2[3];
  float lse = mx + logf(sum);
  float4* q = (float4*)(out + (size_t)b*VV);
  for (int i = t; i < 1250; i += 256){
    bf16x8 v = p[i];
    float4 o0, o1;
    o0.x=(float)v[0]-lse; o0.y=(float)v[1]-lse; o0.z=(float)v[2]-lse; o0.w=(float)v[3]-lse;
    o1.x=(float)v[4]-lse; o1.y=(float)v[5]-lse; o1.z=(float)v[6]-lse; o1.w=(float)v[7]-lse;
    q[i*2]   = o0;
    q[i*2+1] = o1;
  }
}

extern "C" void kernel_launch(void* const* d_in, const int* in_sizes, int n_in,
                              void* d_out_, int out_size, void* d_ws, size_t ws_size,
                              hipStream_t stream){
  const float* x     = (const float*)d_in[0];
  const float* att   = (const float*)d_in[1];
  const float* inputs= (const float*)d_in[2];
  const float* Wa2a  = (const float*)d_in[3];
  const float* ba2a  = (const float*)d_in[4];
  const float* Wh2a  = (const float*)d_in[5];
  const float* bh2a  = (const float*)d_in[6];
  const float* wd2d  = (const float*)d_in[7];
  // d_in[8] = bd2d : uniform pre-softmax scalar -> softmax-invariant, unused
  const float* Wi2h  = (const float*)d_in[9];
  const float* bi2h  = (const float*)d_in[10];
  const float* Wh2h  = (const float*)d_in[11];
  const float* bh2h  = (const float*)d_in[12];
  const float* Wr2a  = (const float*)d_in[13];
  const float* br2a  = (const float*)d_in[14];
  const float* Wproj = (const float*)d_in[15];
  const float* bproj = (const float*)d_in[16];
  float* d_out = (float*)d_out_;

  char* wsp = (char*)d_ws;
  auto alloc = [&](size_t bytes)->char*{
    char* p = wsp;
    wsp += (bytes + 255) & ~(size_t)255;
    return p;
  };
  __bf16* Wa2a_p   = (__bf16*)alloc((size_t)256*RR*2);
  __bf16* Wh2a_pad = (__bf16*)alloc((size_t)256*RR*2);
  __bf16* Wcat_bf  = (__bf16*)alloc((size_t)2048*1536*2);
  __bf16* Wproj_bf = (__bf16*)alloc((size_t)10048*RR*2);
  __bf16* inp_bf   = (__bf16*)alloc((size_t)512*RR*2);
  float* ba_pad = (float*)alloc(256*4);
  float* wd_pad = (float*)alloc(256*4);
  float* bcat   = (float*)alloc(2048*4);
  float* att_h  = (float*)alloc((size_t)2*MATT*4);
  float* score  = (float*)alloc((size_t)2*MATT*4);
  __bf16* Xcat0 = (__bf16*)alloc((size_t)BB*1536*2);
  __bf16* Xcat1 = (__bf16*)alloc((size_t)BB*1536*2);
  float* sums   = (float*)alloc((size_t)BB*2048*4);
  __bf16* h1_bf = (__bf16*)alloc((size_t)BB*RR*2);
  __bf16* logits= (__bf16*)alloc((size_t)BB*VV*2);

  // one fused prep launch
  prep_all_k<<<8618, 256, 0, stream>>>(
      Wa2a, Wh2a, Wproj, inputs, Wi2h, Wh2h, Wr2a, ba2a, wd2d, bi2h, bh2h, br2a,
      Wa2a_p, Wh2a_pad, Wproj_bf, inp_bf, Wcat_bf, ba_pad, wd_pad, bcat);

  // att_h for both layers (fixed inputs): [512 rows][196]
  gemm3_k<0><<<dim3(4,16), 256, 0, stream>>>(inp_bf, Wh2a_pad, bh2a, att_h, AA, 512, 8);

  // attention
  att_score5s_k<<<784, 256, 0, stream>>>(att, Wa2a_p, ba_pad, wd_pad, att_h, score);
  attres_sm_k<<<256, 512, 0, stream>>>(att, score, x, inputs, Xcat0, Xcat1);

  // layer 0
  gemm3_k<0><<<dim3(32,8), 256, 0, stream>>>(Xcat0, Wcat_bf, bcat, sums, 2048, 1536, 24);
  gate_k<<<512, 256, 0, stream>>>(sums, inputs, d_out, d_out + 131072, Xcat1, 1536);
  // layer 1
  gemm3_k<0><<<dim3(32,8), 256, 0, stream>>>(Xcat1, Wcat_bf, bcat, sums, 2048, 1536, 24);
  gate_k<<<512, 256, 0, stream>>>(sums, inputs + 2*131072, d_out + 2*131072, d_out + 3*131072, h1_bf, 512);

  // projection (bf16 logits) + log_softmax
  gemm3_k<1><<<dim3(157,8), 256, 0, stream>>>(h1_bf, Wproj_bf, bproj, logits, VV, 512, 8);
  logsoftmaxb_k<<<256, 256, 0, stream>>>(logits, d_out + 4*131072);
}